// Round 7
// baseline (421.305 us; speedup 1.0000x reference)
//
#include <hip/hip_runtime.h>
#include <cstdint>
#include <cstddef>

// Problem constants
#define BB   64
#define NN   197
#define CC   768
#define HH   12
#define THD  16          // TOTAL_HEADS
#define DD   64
#define MROWS (BB*NN)    // 12608
#define QKVN (THD*DD)    // 1024
#define SCALE_ 0.125f
#define ATTS 208         // r1 region sizing (legacy)
#define KPAD 224         // P row k-padding (7*32)

typedef unsigned short u16;
typedef __attribute__((ext_vector_type(2))) float f32x2;
typedef __attribute__((ext_vector_type(4))) float f32x4;
typedef __attribute__((ext_vector_type(8))) short s16x8;
typedef __attribute__((ext_vector_type(2))) unsigned int u32x2;
typedef __attribute__((address_space(1))) unsigned int as1_u32;
typedef __attribute__((address_space(3))) unsigned int as3_u32;

__device__ __forceinline__ float bf2f(u16 u) {
  union { unsigned int i; float f; } x; x.i = ((unsigned int)u) << 16; return x.f;
}
__device__ __forceinline__ u16 f2bf(float f) {
  unsigned int x = __builtin_bit_cast(unsigned int, f);
  unsigned int r = (x + 0x7fffu + ((x >> 16) & 1u)) >> 16;   // RNE
  return (u16)r;
}
__device__ __forceinline__ void gl_lds16(const u16* g, u16* l) {
  __builtin_amdgcn_global_load_lds((const as1_u32*)g, (as3_u32*)l, 16, 0, 0);
}

// ---------------- x (f32) -> bf16, 8 elems/thread ---------------------------
__global__ __launch_bounds__(256) void k_cvt_x(const float* __restrict__ src,
                                               u16* __restrict__ dst, int n8) {
  int i = blockIdx.x * 256 + threadIdx.x;
  if (i >= n8) return;
  const float4* s = (const float4*)src;
  float4 a = s[2 * i], b = s[2 * i + 1];
  ushort4 lo, hi;
  lo.x = f2bf(a.x); lo.y = f2bf(a.y); lo.z = f2bf(a.z); lo.w = f2bf(a.w);
  hi.x = f2bf(b.x); hi.y = f2bf(b.y); hi.z = f2bf(b.z); hi.w = f2bf(b.w);
  ((ushort4*)dst)[2 * i] = lo;
  ((ushort4*)dst)[2 * i + 1] = hi;
}

// ---------------- weight transpose+convert f32 (R,Ccol) -> bf16 (Ccol,R) ----
__global__ __launch_bounds__(256) void k_transpose(const float* __restrict__ in,
                                                   u16* __restrict__ out,
                                                   int R, int Ccol) {
  __shared__ u16 tile[32][33];
  int c0 = blockIdx.x * 32, r0 = blockIdx.y * 32;
  int tx = threadIdx.x & 31, ty = threadIdx.x >> 5;
#pragma unroll
  for (int i = 0; i < 32; i += 8) {
    int r = r0 + ty + i, c = c0 + tx;
    tile[ty + i][tx] = (r < R && c < Ccol) ? f2bf(in[(size_t)r * Ccol + c]) : (u16)0;
  }
  __syncthreads();
#pragma unroll
  for (int i = 0; i < 32; i += 8) {
    int cc = c0 + ty + i, rr = r0 + tx;
    if (cc < Ccol && rr < R) out[(size_t)cc * R + rr] = tile[tx][ty + i];
  }
}

// ---------------- mw12[n*197+m][12] = masks@mproj + mbase (verified R15) ----
__global__ __launch_bounds__(256) void k_mw(const float* __restrict__ masks,
                                            const float* __restrict__ mproj,
                                            const float* __restrict__ mbase,
                                            float* __restrict__ mw12) {
  int i = blockIdx.x * 256 + threadIdx.x;
  if (i >= NN * NN) return;
  float l0 = masks[(size_t)i * 3], l1 = masks[(size_t)i * 3 + 1], l2 = masks[(size_t)i * 3 + 2];
#pragma unroll
  for (int h = 0; h < 12; h++)
    mw12[(size_t)i * 12 + h] = mbase[h] + l0 * mproj[h] + l1 * mproj[12 + h] + l2 * mproj[24 + h];
}

// ---------------- bf16 MFMA GEMM (R14, measured ~50us, unchanged) -----------
__global__ __launch_bounds__(512, 2) void k_gemm_bt(const u16* __restrict__ A,
                                                    const u16* __restrict__ Bt,
                                                    const float* __restrict__ bias,
                                                    void* __restrict__ Cout,
                                                    int M, int Nn, int K,
                                                    int write_bf16) {
  __shared__ u16 As[3][256 * 32];
  __shared__ u16 Bs[3][256 * 32];
  int t = threadIdx.x;
  int w = t >> 6, lane = t & 63;

  int NT = gridDim.y;
  int nwg = gridDim.x * gridDim.y;
  int d = blockIdx.y * gridDim.x + blockIdx.x;
  int q8 = nwg >> 3, r8 = nwg & 7;
  int xcd = d & 7, j = d >> 3;
  int g = (xcd < r8 ? xcd * (q8 + 1) : r8 * (q8 + 1) + (xcd - r8) * q8) + j;
  int mt = g / NT, nt_ = g - mt * NT;
  int m0 = mt * 256, n0 = nt_ * 256;

  int wm = w >> 2, wn = w & 3;

  f32x4 acc[8][4];
#pragma unroll
  for (int i = 0; i < 8; i++)
#pragma unroll
    for (int j2 = 0; j2 < 4; j2++)
#pragma unroll
      for (int e = 0; e < 4; e++) acc[i][j2][e] = 0.f;

  int lrow4 = lane >> 2;
  int lkc = (lane & 3) * 8;

  auto stage = [&](int buf, int kk) {
#pragma unroll
    for (int rc = 0; rc < 2; rc++) {
      int c = w + rc * 8;
      int row = c * 16 + lrow4;
      int ga = m0 + row; if (ga >= M) ga = M - 1;
      gl_lds16(A + (size_t)ga * K + kk + lkc, &As[buf][c * 512]);
      gl_lds16(Bt + (size_t)(n0 + row) * K + kk + lkc, &Bs[buf][c * 512]);
    }
  };

  auto compute = [&](int buf) {
    int r16 = lane & 15, k8 = (lane >> 4) * 8;
    s16x8 af[8], bfv[4];
#pragma unroll
    for (int s = 0; s < 8; s++)
      af[s] = *(const s16x8*)&As[buf][(wm * 128 + s * 16 + r16) * 32 + k8];
#pragma unroll
    for (int s = 0; s < 4; s++)
      bfv[s] = *(const s16x8*)&Bs[buf][(wn * 64 + s * 16 + r16) * 32 + k8];
#pragma unroll
    for (int sm = 0; sm < 8; sm++)
#pragma unroll
      for (int sn = 0; sn < 4; sn++)
        acc[sm][sn] = __builtin_amdgcn_mfma_f32_16x16x32_bf16(af[sm], bfv[sn], acc[sm][sn], 0, 0, 0);
  };

  int nt = K >> 5;
  stage(0, 0);
  stage(1, 32);
  for (int tt = 0; tt < nt - 2; ++tt) {
    stage((tt + 2) % 3, (tt + 2) * 32);
    asm volatile("s_waitcnt vmcnt(8)" ::: "memory");
    __builtin_amdgcn_sched_barrier(0);
    __builtin_amdgcn_s_barrier();
    compute(tt % 3);
    __builtin_amdgcn_s_barrier();
  }
  asm volatile("s_waitcnt vmcnt(4)" ::: "memory");
  __builtin_amdgcn_sched_barrier(0);
  __builtin_amdgcn_s_barrier();
  compute((nt - 2) % 3);
  __builtin_amdgcn_s_barrier();
  asm volatile("s_waitcnt vmcnt(0)" ::: "memory");
  __builtin_amdgcn_sched_barrier(0);
  __builtin_amdgcn_s_barrier();
  compute((nt - 1) % 3);

  u16*   Cb = (u16*)Cout;
  float* Cf = (float*)Cout;
  int quad = lane >> 4, col = lane & 15;
#pragma unroll
  for (int sn = 0; sn < 4; sn++) {
    int gn = n0 + wn * 64 + sn * 16 + col;
    float bv = bias[gn];
#pragma unroll
    for (int sm = 0; sm < 8; sm++) {
      int gmb = m0 + wm * 128 + sm * 16 + quad * 4;
#pragma unroll
      for (int i = 0; i < 4; i++) {
        int gm = gmb + i;
        if (gm < M) {
          float v = acc[sm][sn][i] + bv;
          if (write_bf16) Cb[(size_t)gm * Nn + gn] = f2bf(v);
          else            Cf[(size_t)gm * Nn + gn] = v;
        }
      }
    }
  }
}

// ---------------- fused QK^T + maskmix/headproj + exp -> P (unscaled), invb -
// One block per (b, 32-row n-tile) = 448 blocks, 512 threads, 42 KB LDS
// (3 blocks/CU). m-loop over 4 tiles of 64. 2 barriers per tile. QK wave
// mapping + phase4 math verified in R15 (passed, same absmax). P written to
// global UNSCALED (exp only); 1/sum written to invb[b][h][n]; k_pv applies it.
__global__ __launch_bounds__(512) void k_qks(const u16* __restrict__ qkv,
                                             const float* __restrict__ mw12,
                                             const float* __restrict__ hpw,
                                             const float* __restrict__ hpb,
                                             u16* __restrict__ P,
                                             float* __restrict__ invb) {
  __shared__ u16 Qs[8 * 512];        // [g][kh][nc] chunks of [16n][32k]  8 KB
  __shared__ u16 Ks[16 * 512];       // [g][kh][mc] chunks of [16m][32k] 16 KB
  __shared__ float S[2 * 32 * 68];   // per-tile logits [g*32+n][68]   17.4 KB
  __shared__ f32x2 hpw_s[72];
  __shared__ f32x2 hpb_s[6];

  int t = threadIdx.x;
  int w = t >> 6, lane = t & 63;
  int bI = blockIdx.x & 63;          // batch (same-b blocks land on one XCD)
  int n0 = (blockIdx.x >> 6) * 32;

  if (t < 72) hpw_s[t] = ((const f32x2*)hpw)[t];
  if (t < 6)  hpb_s[t] = ((const f32x2*)hpb)[t];

  int r16 = lane & 15, k8 = (lane >> 4) * 8;
  int quad = lane >> 4, col = lane & 15;

  auto stageK = [&](int mm0) {
#pragma unroll
    for (int rc = 0; rc < 2; rc++) {
      int c = w + rc * 8;
      int gg = c >> 3, kh = (c >> 2) & 1, mc = c & 3;
      int m = mm0 + mc * 16 + (lane >> 2); if (m > NN - 1) m = NN - 1;
      int k = kh * 32 + (lane & 3) * 8;
      gl_lds16(qkv + (size_t)(bI * NN + m) * QKVN + 2 * DD + gg * DD + k, &Ks[c * 512]);
    }
  };

  // prologue: Q (chunk w) + K tile 0
  {
    int gg = w >> 2, kh = (w >> 1) & 1, nc = w & 1;
    int n = n0 + nc * 16 + (lane >> 2); if (n > NN - 1) n = NN - 1;
    int k = kh * 32 + (lane & 3) * 8;
    gl_lds16(qkv + (size_t)(bI * NN + n) * QKVN + gg * DD + k, &Qs[w * 512]);
  }
  stageK(0);
  __syncthreads();

  // phase4 thread mapping
  int pn = t >> 4, tm = t & 15;
  int validn = (n0 + pn) < NN;
  int nG = n0 + pn; if (nG > NN - 1) nG = NN - 1;

  f32x2 lsum[6];
#pragma unroll
  for (int k = 0; k < 6; k++) { lsum[k].x = 0.f; lsum[k].y = 0.f; }

  int qg = w >> 2, mq = w & 3;       // QK wave roles: (group, m-quarter)

  for (int mt = 0; mt < 4; ++mt) {
    int m0 = mt * 64;

    // ---- QK: S[g][n][m] = SCALE * q.k ----
    {
      f32x4 qa[2];
#pragma unroll
      for (int nc = 0; nc < 2; nc++)
#pragma unroll
        for (int e = 0; e < 4; e++) qa[nc][e] = 0.f;
#pragma unroll
      for (int kh = 0; kh < 2; kh++) {
        s16x8 bk = *(const s16x8*)&Ks[((qg * 2 + kh) * 4 + mq) * 512 + r16 * 32 + k8];
#pragma unroll
        for (int nc = 0; nc < 2; nc++) {
          s16x8 aq = *(const s16x8*)&Qs[((qg * 2 + kh) * 2 + nc) * 512 + r16 * 32 + k8];
          qa[nc] = __builtin_amdgcn_mfma_f32_16x16x32_bf16(aq, bk, qa[nc], 0, 0, 0);
        }
      }
#pragma unroll
      for (int nc = 0; nc < 2; nc++)
#pragma unroll
        for (int i = 0; i < 4; i++)
          S[(qg * 32 + nc * 16 + quad * 4 + i) * 68 + mq * 16 + col] = qa[nc][i] * SCALE_;
    }
    __syncthreads();   // S ready; Ks fully consumed

    if (mt < 3) stageK(m0 + 64);   // DMA next K tile (drained at next barrier)

    // ---- phase4: maskmix + headproj + exp -> P global (unscaled), lsum ----
    {
      const f32x4* S4 = (const f32x4*)S;
      f32x4 s0 = S4[pn * 17 + tm];
      f32x4 s1 = S4[(32 + pn) * 17 + tm];
      int gm0 = m0 + tm * 4;
      int gmc = gm0 > NN - 1 ? NN - 1 : gm0;
      const f32x4* mwp = (const f32x4*)(mw12 + ((size_t)nG * NN + gmc) * 12);
      unsigned int pk[12][2];
#pragma unroll
      for (int h = 0; h < 12; h++) { pk[h][0] = 0u; pk[h][1] = 0u; }
#pragma unroll
      for (int j = 0; j < 4; j++) {
        int valid = (gm0 + j) < NN;
        f32x4 w0 = mwp[j * 3 + 0], w1 = mwp[j * 3 + 1], w2 = mwp[j * 3 + 2];
        float a0 = s0[j], a1 = s1[j];
        f32x2 pre[6];
        pre[0] = *(const f32x2*)&w0 * a0;
        pre[1] = *((const f32x2*)&w0 + 1) * a0;
        pre[2] = *(const f32x2*)&w1 * a0;
        pre[3] = *((const f32x2*)&w1 + 1) * a1;
        pre[4] = *(const f32x2*)&w2 * a1;
        pre[5] = *((const f32x2*)&w2 + 1) * a1;
#pragma unroll
        for (int k = 0; k < 6; k++) {
          pre[k].x = pre[k].x > 0.f ? pre[k].x : 0.f;
          pre[k].y = pre[k].y > 0.f ? pre[k].y : 0.f;
        }
        f32x2 a12[6];
#pragma unroll
        for (int k = 0; k < 6; k++) a12[k] = hpb_s[k];
#pragma unroll
        for (int h = 0; h < 12; h++) {
          float p = (h & 1) ? pre[h >> 1].y : pre[h >> 1].x;
#pragma unroll
          for (int k = 0; k < 6; k++) a12[k] += p * hpw_s[h * 6 + k];
        }
#pragma unroll
        for (int k = 0; k < 6; k++) {
          float ex = 0.f, ey = 0.f;
          if (valid) {
            ex = __expf(a12[k].x); ey = __expf(a12[k].y);
            lsum[k].x += ex; lsum[k].y += ey;
          }
          pk[2 * k][j >> 1]     |= (unsigned int)f2bf(ex) << ((j & 1) * 16);
          pk[2 * k + 1][j >> 1] |= (unsigned int)f2bf(ey) << ((j & 1) * 16);
        }
      }
      if (validn && gm0 < KPAD) {
#pragma unroll
        for (int h = 0; h < 12; h++) {
          u32x2 val; val.x = pk[h][0]; val.y = pk[h][1];
          *(u32x2*)&P[((size_t)(bI * HH + h) * NN + nG) * KPAD + gm0] = val;
        }
      }
    }
    __syncthreads();   // phase4 done (S reusable); K(t+1) loads drained
  }

  // ---- lsum reduce over 16 tm lanes -> invb[b][h][n] ----
#pragma unroll
  for (int off = 8; off; off >>= 1)
#pragma unroll
    for (int k = 0; k < 6; k++) {
      lsum[k].x += __shfl_xor(lsum[k].x, off, 16);
      lsum[k].y += __shfl_xor(lsum[k].y, off, 16);
    }
  if (tm == 0 && validn) {
#pragma unroll
    for (int k = 0; k < 6; k++) {
      invb[(size_t)(bI * HH + 2 * k) * NN + nG]     = 1.f / lsum[k].x;
      invb[(size_t)(bI * HH + 2 * k + 1) * NN + nG] = 1.f / lsum[k].y;
    }
  }
}

// ---------------- PV via MFMA (R14 structure + invb scaling in epilogue) ----
__global__ __launch_bounds__(256) void k_pv(const u16* __restrict__ P,
                                            const u16* __restrict__ qkv,
                                            const float* __restrict__ invb,
                                            u16* __restrict__ aout) {
  __shared__ u16 As[2][128 * 32];  // P rows [n][32 m] per half
  __shared__ u16 Bs[2][64 * 32];   // VT [d][32 m] per half
  int t = threadIdx.x;
  int w = t >> 6, lane = t & 63;
  int bh = blockIdx.y, b = bh / HH, h = bh - b * HH;
  int n0 = blockIdx.x * 128;

  f32x4 acc[2][4];
#pragma unroll
  for (int i = 0; i < 2; i++)
#pragma unroll
    for (int j = 0; j < 4; j++)
#pragma unroll
      for (int e = 0; e < 4; e++) acc[i][j][e] = 0.f;

  int lrow4 = lane >> 2, lkc = (lane & 3) * 8;
  int vml = t & 31, vd0 = (t >> 5) * 8;    // B-staging mapping

  for (int k0 = 0; k0 < KPAD; k0 += 64) {
    int nh = (KPAD - k0 >= 64) ? 2 : 1;
    for (int half = 0; half < nh; half++) {
      int kk = k0 + half * 32;
#pragma unroll
      for (int rc = 0; rc < 2; rc++) {
        int c = w + rc * 4;
        int row = c * 16 + lrow4;
        int gn = n0 + row; if (gn > NN - 1) gn = NN - 1;
        gl_lds16(P + ((size_t)bh * NN + gn) * KPAD + kk + lkc, &As[half][c * 512]);
      }
      {
        int m = kk + vml;
        u16 v8[8];
        if (m < NN) {
          const ushort4* vp = (const ushort4*)(qkv + (size_t)(b * NN + m) * QKVN + (4 + h) * DD + vd0);
          ushort4 lo = vp[0], hi = vp[1];
          v8[0] = lo.x; v8[1] = lo.y; v8[2] = lo.z; v8[3] = lo.w;
          v8[4] = hi.x; v8[5] = hi.y; v8[6] = hi.z; v8[7] = hi.w;
        } else {
#pragma unroll
          for (int j = 0; j < 8; j++) v8[j] = 0;
        }
#pragma unroll
        for (int j = 0; j < 8; j++) Bs[half][(vd0 + j) * 32 + vml] = v8[j];
      }
    }
    __syncthreads();
    int r16 = lane & 15, k8 = (lane >> 4) * 8;
    for (int half = 0; half < nh; half++) {
      s16x8 af[2], bfv[4];
#pragma unroll
      for (int s = 0; s < 2; s++)
        af[s] = *(const s16x8*)&As[half][(w * 32 + s * 16 + r16) * 32 + k8];
#pragma unroll
      for (int s = 0; s < 4; s++)
        bfv[s] = *(const s16x8*)&Bs[half][(s * 16 + r16) * 32 + k8];
#pragma unroll
      for (int sm = 0; sm < 2; sm++)
#pragma unroll
        for (int sn = 0; sn < 4; sn++)
          acc[sm][sn] = __builtin_amdgcn_mfma_f32_16x16x32_bf16(af[sm], bfv[sn], acc[sm][sn], 0, 0, 0);
    }
    __syncthreads();
  }
  int quad = lane >> 4, col = lane & 15;
#pragma unroll
  for (int sn = 0; sn < 4; sn++) {
    int gd = sn * 16 + col;                         // d
#pragma unroll
    for (int sm = 0; sm < 2; sm++) {
      int gnb = n0 + w * 32 + sm * 16 + quad * 4;   // n
#pragma unroll
      for (int i = 0; i < 4; i++) {
        int gn = gnb + i;
        if (gn < NN) {
          float iv = invb[(size_t)bh * NN + gn];
          aout[(size_t)(b * NN + gn) * CC + h * DD + gd] = f2bf(acc[sm][sn][i] * iv);
        }
      }
    }
  }
}

extern "C" void kernel_launch(void* const* d_in, const int* in_sizes, int n_in,
                              void* d_out, int out_size, void* d_ws, size_t ws_size,
                              hipStream_t stream) {
  const float* x     = (const float*)d_in[0];
  const float* qkv_w = (const float*)d_in[1];
  const float* qkv_b = (const float*)d_in[2];
  const float* masks = (const float*)d_in[3];
  const float* mproj = (const float*)d_in[4];
  const float* mbase = (const float*)d_in[5];
  const float* hpw   = (const float*)d_in[6];
  const float* hpb   = (const float*)d_in[7];
  const float* projw = (const float*)d_in[8];
  const float* projb = (const float*)d_in[9];

  char* ws = (char*)d_ws;
  size_t off = 0;
  auto alloc = [&](size_t bytes) {
    char* p = ws + off; off = (off + bytes + 255) & ~(size_t)255; return p;
  };
  // region1: xbf (19.4MB) -> aout (19.4MB), disjoint lifetimes
  char*  r1   = alloc((size_t)BB * 2 * NN * ATTS * 4);
  u16*   xbf  = (u16*)r1;
  u16*   aout = (u16*)r1;
  u16*   qkv  = (u16*)alloc((size_t)MROWS * QKVN * 2);              // 25.8 MB
  u16*   P    = (u16*)alloc((size_t)BB * HH * NN * KPAD * 2);       // 67.8 MB
  u16*   wt1  = (u16*)alloc((size_t)QKVN * CC * 2);                 //  1.6 MB
  u16*   wt2  = (u16*)alloc((size_t)CC * CC * 2);                   //  1.2 MB
  float* mw12 = (float*)alloc((size_t)NN * NN * 12 * 4 + 1024);     //  1.9 MB
  float* invb = (float*)alloc((size_t)BB * HH * NN * 4);            //  0.6 MB

  int n8 = MROWS * CC / 8;
  k_cvt_x<<<(n8 + 255) / 256, 256, 0, stream>>>(x, xbf, n8);
  k_transpose<<<dim3(QKVN / 32, CC / 32), 256, 0, stream>>>(qkv_w, wt1, CC, QKVN);
  k_transpose<<<dim3(CC / 32, CC / 32), 256, 0, stream>>>(projw, wt2, CC, CC);
  k_mw<<<(NN * NN + 255) / 256, 256, 0, stream>>>(masks, mproj, mbase, mw12);
  // qkv = x @ qkv_w + qkv_b (bf16)
  k_gemm_bt<<<dim3((MROWS + 255) / 256, QKVN / 256), 512, 0, stream>>>(
      xbf, wt1, qkv_b, qkv, MROWS, QKVN, CC, 1);
  // fused QK+softmax-front: P (unscaled exp) + invb
  k_qks<<<dim3(7 * BB), 512, 0, stream>>>(qkv, mw12, hpw, hpb, P, invb);
  // aout = (P @ V) * invb
  k_pv<<<dim3(2, BB * HH), 256, 0, stream>>>(P, qkv, invb, aout);
  // out = aout @ proj_w + proj_b (f32)
  k_gemm_bt<<<dim3((MROWS + 255) / 256, CC / 256), 512, 0, stream>>>(
      aout, wt2, projb, d_out, MROWS, CC, CC, 0);
}

// Round 8
// 244.198 us; speedup vs baseline: 1.7253x; 1.7253x over previous
//
#include <hip/hip_runtime.h>
#include <cstdint>
#include <cstddef>

// Problem constants
#define BB   64
#define NN   197
#define CC   768
#define HH   12
#define THD  16          // TOTAL_HEADS
#define DD   64
#define MROWS (BB*NN)    // 12608
#define QKVN (THD*DD)    // 1024
#define SCALE_ 0.125f
#define ATTS 208         // att row stride (f32)
#define KPAD 224         // P row k-padding (7*32)
#define SSTR 240         // S row stride (f32): 240%32=16 -> 2-way max (free)

typedef unsigned short u16;
typedef __attribute__((ext_vector_type(2))) float f32x2;
typedef __attribute__((ext_vector_type(4))) float f32x4;
typedef __attribute__((ext_vector_type(8))) short s16x8;
typedef __attribute__((address_space(1))) unsigned int as1_u32;
typedef __attribute__((address_space(3))) unsigned int as3_u32;

__device__ __forceinline__ float bf2f(u16 u) {
  union { unsigned int i; float f; } x; x.i = ((unsigned int)u) << 16; return x.f;
}
__device__ __forceinline__ u16 f2bf(float f) {
  unsigned int x = __builtin_bit_cast(unsigned int, f);
  unsigned int r = (x + 0x7fffu + ((x >> 16) & 1u)) >> 16;   // RNE
  return (u16)r;
}
__device__ __forceinline__ void gl_lds16(const u16* g, u16* l) {
  __builtin_amdgcn_global_load_lds((const as1_u32*)g, (as3_u32*)l, 16, 0, 0);
}

// ---------------- x (f32) -> bf16, 8 elems/thread ---------------------------
__global__ __launch_bounds__(256) void k_cvt_x(const float* __restrict__ src,
                                               u16* __restrict__ dst, int n8) {
  int i = blockIdx.x * 256 + threadIdx.x;
  if (i >= n8) return;
  const float4* s = (const float4*)src;
  float4 a = s[2 * i], b = s[2 * i + 1];
  ushort4 lo, hi;
  lo.x = f2bf(a.x); lo.y = f2bf(a.y); lo.z = f2bf(a.z); lo.w = f2bf(a.w);
  hi.x = f2bf(b.x); hi.y = f2bf(b.y); hi.z = f2bf(b.z); hi.w = f2bf(b.w);
  ((ushort4*)dst)[2 * i] = lo;
  ((ushort4*)dst)[2 * i + 1] = hi;
}

// ---------------- weight transpose+convert f32 (R,Ccol) -> bf16 (Ccol,R) ----
__global__ __launch_bounds__(256) void k_transpose(const float* __restrict__ in,
                                                   u16* __restrict__ out,
                                                   int R, int Ccol) {
  __shared__ u16 tile[32][33];
  int c0 = blockIdx.x * 32, r0 = blockIdx.y * 32;
  int tx = threadIdx.x & 31, ty = threadIdx.x >> 5;
#pragma unroll
  for (int i = 0; i < 32; i += 8) {
    int r = r0 + ty + i, c = c0 + tx;
    tile[ty + i][tx] = (r < R && c < Ccol) ? f2bf(in[(size_t)r * Ccol + c]) : (u16)0;
  }
  __syncthreads();
#pragma unroll
  for (int i = 0; i < 32; i += 8) {
    int cc = c0 + ty + i, rr = r0 + tx;
    if (cc < Ccol && rr < R) out[(size_t)cc * R + rr] = tile[tx][ty + i];
  }
}

// ---------------- bf16 MFMA GEMM (R14 pipeline + R17 LDS-staged bf16 epilogue)
// 256x256 tile, 8 waves, BK=32, triple-buffer, counted vmcnt(8) (R14 verified).
// R17: write_bf16 epilogue stages C through LDS (2 passes x 128 rows) and
// writes full rows in 16-B chunks. The old per-lane 2-B stores covered only
// 32 B per 16 lanes = half a 64-B sector -> HBM RMW: measured WRITE 62 MB for
// a 25.8 MB C (2.4x). f32 path (already full-sector) unchanged.
__global__ __launch_bounds__(512, 2) void k_gemm_bt(const u16* __restrict__ A,
                                                    const u16* __restrict__ Bt,
                                                    const float* __restrict__ bias,
                                                    void* __restrict__ Cout,
                                                    int M, int Nn, int K,
                                                    int write_bf16) {
  __shared__ u16 SHG[49152];   // As=[0,24576) 3x8192 | Bs=[24576,49152) 3x8192
                               // epilogue reuse: O[128][272] = 34816 u16
  u16* As = SHG;
  u16* Bs = SHG + 24576;
  int t = threadIdx.x;
  int w = t >> 6, lane = t & 63;

  // XCD-chunked bijective remap (m204)
  int NT = gridDim.y;
  int nwg = gridDim.x * gridDim.y;
  int d = blockIdx.y * gridDim.x + blockIdx.x;
  int q8 = nwg >> 3, r8 = nwg & 7;
  int xcd = d & 7, j = d >> 3;
  int g = (xcd < r8 ? xcd * (q8 + 1) : r8 * (q8 + 1) + (xcd - r8) * q8) + j;
  int mt = g / NT, nt_ = g - mt * NT;
  int m0 = mt * 256, n0 = nt_ * 256;

  int wm = w >> 2, wn = w & 3;

  f32x4 acc[8][4];
#pragma unroll
  for (int i = 0; i < 8; i++)
#pragma unroll
    for (int j2 = 0; j2 < 4; j2++)
#pragma unroll
      for (int e = 0; e < 4; e++) acc[i][j2][e] = 0.f;

  int lrow4 = lane >> 2;
  int lkc = (lane & 3) * 8;

  auto stage = [&](int buf, int kk) {
#pragma unroll
    for (int rc = 0; rc < 2; rc++) {
      int c = w + rc * 8;
      int row = c * 16 + lrow4;
      int ga = m0 + row; if (ga >= M) ga = M - 1;
      gl_lds16(A + (size_t)ga * K + kk + lkc, &As[buf * 8192 + c * 512]);
      gl_lds16(Bt + (size_t)(n0 + row) * K + kk + lkc, &Bs[buf * 8192 + c * 512]);
    }
  };

  auto compute = [&](int buf) {
    int r16 = lane & 15, k8 = (lane >> 4) * 8;
    s16x8 af[8], bfv[4];
#pragma unroll
    for (int s = 0; s < 8; s++)
      af[s] = *(const s16x8*)&As[buf * 8192 + (wm * 128 + s * 16 + r16) * 32 + k8];
#pragma unroll
    for (int s = 0; s < 4; s++)
      bfv[s] = *(const s16x8*)&Bs[buf * 8192 + (wn * 64 + s * 16 + r16) * 32 + k8];
#pragma unroll
    for (int sm = 0; sm < 8; sm++)
#pragma unroll
      for (int sn = 0; sn < 4; sn++)
        acc[sm][sn] = __builtin_amdgcn_mfma_f32_16x16x32_bf16(af[sm], bfv[sn], acc[sm][sn], 0, 0, 0);
  };

  int nt = K >> 5;
  stage(0, 0);
  stage(1, 32);
  for (int tt = 0; tt < nt - 2; ++tt) {
    stage((tt + 2) % 3, (tt + 2) * 32);
    asm volatile("s_waitcnt vmcnt(8)" ::: "memory");
    __builtin_amdgcn_sched_barrier(0);
    __builtin_amdgcn_s_barrier();
    compute(tt % 3);
    __builtin_amdgcn_s_barrier();
  }
  asm volatile("s_waitcnt vmcnt(4)" ::: "memory");
  __builtin_amdgcn_sched_barrier(0);
  __builtin_amdgcn_s_barrier();
  compute((nt - 2) % 3);
  __builtin_amdgcn_s_barrier();
  asm volatile("s_waitcnt vmcnt(0)" ::: "memory");
  __builtin_amdgcn_sched_barrier(0);
  __builtin_amdgcn_s_barrier();
  compute((nt - 1) % 3);

  int quad = lane >> 4, col = lane & 15;
  if (write_bf16) {
    u16* Cb = (u16*)Cout;
    u16* O = SHG;                        // [128][272] u16 (272: 2-way-max banks)
    __syncthreads();                     // all LDS reads done before O overwrite
#pragma unroll
    for (int p = 0; p < 2; p++) {
      if (wm == p) {
#pragma unroll
        for (int sn = 0; sn < 4; sn++) {
          int gn = n0 + wn * 64 + sn * 16 + col;
          float bv = bias[gn];
#pragma unroll
          for (int sm = 0; sm < 8; sm++)
#pragma unroll
            for (int i = 0; i < 4; i++)
              O[(sm * 16 + quad * 4 + i) * 272 + wn * 64 + sn * 16 + col] =
                  f2bf(acc[sm][sn][i] + bv);
        }
      }
      __syncthreads();
      // copy out: 128 rows x 32 chunks of 16 B; 32 lanes cover a full row
#pragma unroll
      for (int it = 0; it < 8; it++) {
        int q = t + it * 512;
        int rl = q >> 5, c8 = q & 31;
        int gm = m0 + p * 128 + rl;
        if (gm < M) {
          s16x8 v = *(const s16x8*)&O[rl * 272 + c8 * 8];
          *(s16x8*)&Cb[(size_t)gm * Nn + n0 + c8 * 8] = v;
        }
      }
      __syncthreads();
    }
  } else {
    float* Cf = (float*)Cout;
#pragma unroll
    for (int sn = 0; sn < 4; sn++) {
      int gn = n0 + wn * 64 + sn * 16 + col;
      float bv = bias[gn];
#pragma unroll
      for (int sm = 0; sm < 8; sm++) {
        int gmb = m0 + wm * 128 + sm * 16 + quad * 4;
#pragma unroll
        for (int i = 0; i < 4; i++) {
          int gm = gmb + i;
          if (gm < M) Cf[(size_t)gm * Nn + gn] = acc[sm][sn][i] + bv;
        }
      }
    }
  }
}

// ---------------- QK^T logits via MFMA (R14 verbatim) -----------------------
__global__ __launch_bounds__(256) void k_qk(const u16* __restrict__ qkv,
                                            float* __restrict__ att) {
  __shared__ u16 As[2][128 * 32];
  __shared__ u16 Bs[2][128 * 32];
  int t = threadIdx.x;
  int w = t >> 6, lane = t & 63;
  int bz = blockIdx.z, b = bz >> 1, g = bz & 1;
  int n0 = blockIdx.x * 128;     // Q rows
  int m0 = blockIdx.y * 128;     // K rows
  int wm = w >> 1, wn = w & 1;

  f32x4 acc[4][4];
#pragma unroll
  for (int i = 0; i < 4; i++)
#pragma unroll
    for (int j = 0; j < 4; j++)
#pragma unroll
      for (int e = 0; e < 4; e++) acc[i][j][e] = 0.f;

  int lrow4 = lane >> 2, lkc = (lane & 3) * 8;

#pragma unroll
  for (int half = 0; half < 2; half++) {
    int kk = half * 32;
#pragma unroll
    for (int rc = 0; rc < 2; rc++) {
      int c = w + rc * 4;
      int row = c * 16 + lrow4;
      int nq = n0 + row; if (nq > NN - 1) nq = NN - 1;
      int mk = m0 + row; if (mk > NN - 1) mk = NN - 1;
      gl_lds16(qkv + (size_t)(b * NN + nq) * QKVN + g * DD + kk + lkc, &As[half][c * 512]);
      gl_lds16(qkv + (size_t)(b * NN + mk) * QKVN + 2 * DD + g * DD + kk + lkc, &Bs[half][c * 512]);
    }
  }
  __syncthreads();
  {
    int r16 = lane & 15, k8 = (lane >> 4) * 8;
#pragma unroll
    for (int half = 0; half < 2; half++) {
      s16x8 af[4], bfv[4];
#pragma unroll
      for (int s = 0; s < 4; s++) {
        af[s]  = *(const s16x8*)&As[half][(wm * 64 + s * 16 + r16) * 32 + k8];
        bfv[s] = *(const s16x8*)&Bs[half][(wn * 64 + s * 16 + r16) * 32 + k8];
      }
#pragma unroll
      for (int sm = 0; sm < 4; sm++)
#pragma unroll
        for (int sn = 0; sn < 4; sn++)
          acc[sm][sn] = __builtin_amdgcn_mfma_f32_16x16x32_bf16(af[sm], bfv[sn], acc[sm][sn], 0, 0, 0);
    }
  }
  int quad = lane >> 4, col = lane & 15;
#pragma unroll
  for (int sn = 0; sn < 4; sn++) {
    int gn = m0 + wn * 64 + sn * 16 + col;          // key index m
#pragma unroll
    for (int sm = 0; sm < 4; sm++) {
      int gmb = n0 + wm * 64 + sm * 16 + quad * 4;  // query index n
#pragma unroll
      for (int i = 0; i < 4; i++) {
        int gm = gmb + i;
        if (gm < NN && gn < NN)
          att[((size_t)bz * NN + gm) * ATTS + gn] = acc[sm][sn][i] * SCALE_;
      }
    }
  }
}

// ---------------- per (b,n): mask-mix + relu + head-proj + softmax -> P -----
// R11/R14 verbatim: SSTR=240, register-cached max pass, deferred 1/sum.
__global__ __launch_bounds__(256) void k_softmax_p(const float* __restrict__ att,
                                                   const float* __restrict__ masks,
                                                   const float* __restrict__ mproj,
                                                   const float* __restrict__ mbase,
                                                   const float* __restrict__ hpw,
                                                   const float* __restrict__ hpb,
                                                   u16* __restrict__ P) {
  __shared__ float S[12][SSTR];
  __shared__ f32x2 hpw_s[72];
  __shared__ f32x2 mp_s[18];
  __shared__ f32x2 mb_s[6], hpb_s[6];
  __shared__ float inv_s[12];
  int t = threadIdx.x;
  int n = blockIdx.x, b = blockIdx.y;

  if (t < 72) hpw_s[t] = ((const f32x2*)hpw)[t];
  if (t < 18) mp_s[t] = ((const f32x2*)mproj)[t];
  if (t < 6) { mb_s[t] = ((const f32x2*)mbase)[t]; hpb_s[t] = ((const f32x2*)hpb)[t]; }
  __syncthreads();

  if (t < NN) {
    int m = t;
    float a0 = att[((size_t)(b * 2 + 0) * NN + n) * ATTS + m];
    float a1 = att[((size_t)(b * 2 + 1) * NN + n) * ATTS + m];
    const float* mk = masks + ((size_t)n * NN + m) * 3;
    float l0 = mk[0], l1 = mk[1], l2 = mk[2];
    f32x2 pre2[6];
#pragma unroll
    for (int k = 0; k < 6; k++) {
      f32x2 wv = mb_s[k] + l0 * mp_s[k] + l1 * mp_s[6 + k] + l2 * mp_s[12 + k];
      float av = (k < 3) ? a0 : a1;
      f32x2 v = wv * av;
      pre2[k].x = v.x > 0.f ? v.x : 0.f;
      pre2[k].y = v.y > 0.f ? v.y : 0.f;
    }
    f32x2 s2[6];
#pragma unroll
    for (int k = 0; k < 6; k++) s2[k] = hpb_s[k];
#pragma unroll
    for (int h = 0; h < 12; h++) {
      float p = (h & 1) ? pre2[h >> 1].y : pre2[h >> 1].x;
#pragma unroll
      for (int k = 0; k < 6; k++) s2[k] += p * hpw_s[h * 6 + k];
    }
#pragma unroll
    for (int k = 0; k < 6; k++) {
      S[2 * k][m] = s2[k].x;
      S[2 * k + 1][m] = s2[k].y;
    }
  } else if (t < KPAD) {
#pragma unroll
    for (int h = 0; h < 12; h++) S[h][t] = 0.f;
  }
  __syncthreads();

  {
    int g = t >> 4, l16 = t & 15;
    if (g < 12) {
      float vals[13];
      float mx = -1e30f;
#pragma unroll
      for (int i = 0; i < 13; i++) {
        int m = l16 + i * 16;
        float x = S[g][m];
        vals[i] = (m < NN) ? x : -1e30f;
        mx = fmaxf(mx, vals[i]);
      }
#pragma unroll
      for (int off = 8; off; off >>= 1) mx = fmaxf(mx, __shfl_xor(mx, off, 16));
      float sum = 0.f;
#pragma unroll
      for (int i = 0; i < 13; i++) {
        int m = l16 + i * 16;
        float e = __expf(vals[i] - mx);
        if (m < NN) { S[g][m] = e; sum += e; }
      }
#pragma unroll
      for (int off = 8; off; off >>= 1) sum += __shfl_xor(sum, off, 16);
      if (l16 == 0) inv_s[g] = 1.f / sum;
    }
  }
  __syncthreads();

  for (int c4 = t; c4 < 672; c4 += 256) {
    int h = c4 / 56;
    int m = (c4 - h * 56) * 4;
    f32x4 v = *(const f32x4*)&S[h][m];
    float iv = inv_s[h];
    ushort4 u;
    u.x = f2bf(v.x * iv); u.y = f2bf(v.y * iv);
    u.z = f2bf(v.z * iv); u.w = f2bf(v.w * iv);
    *(ushort4*)(P + ((size_t)(b * HH + h) * NN + n) * KPAD + m) = u;
  }
}

// ---------------- PV via MFMA (R17: single 224-row block; LDS-staged aout) --
// One block per (b*12+h) = 768 blocks, 256 threads. M=224(n,clamped) N=64(d)
// K=224(m). V staged ONCE per block (was twice with the 2 n-tile grid).
// aout staged through LDS then written as full 128-B rows (old per-lane 2-B
// stores were half-sector RMW like the gemm epilogue).
__global__ __launch_bounds__(256) void k_pv(const u16* __restrict__ P,
                                            const u16* __restrict__ qkv,
                                            u16* __restrict__ aout) {
  __shared__ u16 SH[18432];   // As=[0,14336) 2x7168 | Bs=[14336,18432) 2x2048
                              // epilogue reuse: O[224][80] = 17920 u16
  u16* As = SH;
  u16* Bs = SH + 14336;
  int t = threadIdx.x;
  int w = t >> 6, lane = t & 63;
  int bh = blockIdx.x, b = bh / HH, h = bh - b * HH;

  f32x4 acc[4][4];
#pragma unroll
  for (int i = 0; i < 4; i++)
#pragma unroll
    for (int j = 0; j < 4; j++)
#pragma unroll
      for (int e = 0; e < 4; e++) acc[i][j][e] = 0.f;

  int lrow4 = lane >> 2, lkc = (lane & 3) * 8;
  int vml = t & 31, vd0 = (t >> 5) * 8;

  for (int k0 = 0; k0 < KPAD; k0 += 64) {
    int nh = (KPAD - k0 >= 64) ? 2 : 1;
    for (int half = 0; half < nh; half++) {
      int kk = k0 + half * 32;
      // A: all 224 P rows (14 chunks of 16) via gl_lds16
#pragma unroll
      for (int rc = 0; rc < 4; rc++) {
        int c = w + rc * 4;
        if (c < 14) {
          int row = c * 16 + lrow4;
          int gn = row > NN - 1 ? NN - 1 : row;
          gl_lds16(P + ((size_t)bh * NN + gn) * KPAD + kk + lkc, &As[half * 7168 + c * 512]);
        }
      }
      // B: V rows -> transposed LDS [d][m]
      {
        int m = kk + vml;
        u16 v8[8];
        if (m < NN) {
          const ushort4* vp = (const ushort4*)(qkv + (size_t)(b * NN + m) * QKVN + (4 + h) * DD + vd0);
          ushort4 lo = vp[0], hi = vp[1];
          v8[0] = lo.x; v8[1] = lo.y; v8[2] = lo.z; v8[3] = lo.w;
          v8[4] = hi.x; v8[5] = hi.y; v8[6] = hi.z; v8[7] = hi.w;
        } else {
#pragma unroll
          for (int j = 0; j < 8; j++) v8[j] = 0;
        }
#pragma unroll
        for (int j = 0; j < 8; j++) Bs[half * 2048 + (vd0 + j) * 32 + vml] = v8[j];
      }
    }
    __syncthreads();
    int r16 = lane & 15, k8 = (lane >> 4) * 8;
    for (int half = 0; half < nh; half++) {
      s16x8 bfv[4];
#pragma unroll
      for (int s = 0; s < 4; s++)
        bfv[s] = *(const s16x8*)&Bs[half * 2048 + (s * 16 + r16) * 32 + k8];
#pragma unroll
      for (int si = 0; si < 4; si++) {
        int smt = w + si * 4;                 // n-subtile 0..13 per wave
        if (smt < 14) {
          s16x8 af = *(const s16x8*)&As[half * 7168 + (smt * 16 + r16) * 32 + k8];
#pragma unroll
          for (int sn = 0; sn < 4; sn++)
            acc[si][sn] = __builtin_amdgcn_mfma_f32_16x16x32_bf16(af, bfv[sn], acc[si][sn], 0, 0, 0);
        }
      }
    }
    __syncthreads();
  }

  // epilogue: dump to O[224][80] (2-way-max banks), then full-row writes
  int quad = lane >> 4, col = lane & 15;
  u16* O = SH;
#pragma unroll
  for (int si = 0; si < 4; si++) {
    int smt = w + si * 4;
    if (smt < 14) {
#pragma unroll
      for (int sn = 0; sn < 4; sn++)
#pragma unroll
        for (int i = 0; i < 4; i++)
          O[(smt * 16 + quad * 4 + i) * 80 + sn * 16 + col] = f2bf(acc[si][sn][i]);
    }
  }
  __syncthreads();
  for (int q = t; q < NN * 8; q += 256) {
    int rl = q >> 3, c8 = q & 7;
    s16x8 v = *(const s16x8*)&O[rl * 80 + c8 * 8];
    *(s16x8*)&aout[(size_t)(b * NN + rl) * CC + h * DD + c8 * 8] = v;
  }
}

extern "C" void kernel_launch(void* const* d_in, const int* in_sizes, int n_in,
                              void* d_out, int out_size, void* d_ws, size_t ws_size,
                              hipStream_t stream) {
  const float* x     = (const float*)d_in[0];
  const float* qkv_w = (const float*)d_in[1];
  const float* qkv_b = (const float*)d_in[2];
  const float* masks = (const float*)d_in[3];
  const float* mproj = (const float*)d_in[4];
  const float* mbase = (const float*)d_in[5];
  const float* hpw   = (const float*)d_in[6];
  const float* hpb   = (const float*)d_in[7];
  const float* projw = (const float*)d_in[8];
  const float* projb = (const float*)d_in[9];

  char* ws = (char*)d_ws;
  size_t off = 0;
  auto alloc = [&](size_t bytes) {
    char* p = ws + off; off = (off + bytes + 255) & ~(size_t)255; return p;
  };
  // region1: xbf (19.4MB) -> att (21.0MB) -> aout (19.4MB), disjoint lifetimes
  char*  r1   = alloc((size_t)BB * 2 * NN * ATTS * 4);
  u16*   xbf  = (u16*)r1;
  float* att  = (float*)r1;
  u16*   aout = (u16*)r1;
  u16*   qkv  = (u16*)alloc((size_t)MROWS * QKVN * 2);          // 25.8 MB
  u16*   P    = (u16*)alloc((size_t)BB * HH * NN * KPAD * 2);   // 67.8 MB
  u16*   wt1  = (u16*)alloc((size_t)QKVN * CC * 2);             //  1.6 MB
  u16*   wt2  = (u16*)alloc((size_t)CC * CC * 2);               //  1.2 MB

  int n8 = MROWS * CC / 8;
  k_cvt_x<<<(n8 + 255) / 256, 256, 0, stream>>>(x, xbf, n8);
  k_transpose<<<dim3(QKVN / 32, CC / 32), 256, 0, stream>>>(qkv_w, wt1, CC, QKVN);
  k_transpose<<<dim3(CC / 32, CC / 32), 256, 0, stream>>>(projw, wt2, CC, CC);
  // qkv = x @ qkv_w + qkv_b (bf16; LDS-staged epilogue)
  k_gemm_bt<<<dim3((MROWS + 255) / 256, QKVN / 256), 512, 0, stream>>>(
      xbf, wt1, qkv_b, qkv, MROWS, QKVN, CC, 1);
  // att[bg][n][m] = SCALE * q.k
  k_qk<<<dim3(2, 2, BB * 2), 256, 0, stream>>>(qkv, att);
  // P[b][h][n][m] (bf16, softmaxed)
  k_softmax_p<<<dim3(NN, BB), 256, 0, stream>>>(att, masks, mproj, mbase, hpw, hpb, P);
  // aout[b][n][h*64+d] = P @ V  (single 224-row block per bh)
  k_pv<<<dim3(BB * HH), 256, 0, stream>>>(P, qkv, aout);
  // out = aout @ proj_w + proj_b (f32, direct epilogue)
  k_gemm_bt<<<dim3((MROWS + 255) / 256, CC / 256), 512, 0, stream>>>(
      aout, wt2, projb, d_out, MROWS, CC, CC, 0);
}

// Round 9
// 240.509 us; speedup vs baseline: 1.7517x; 1.0153x over previous
//
#include <hip/hip_runtime.h>
#include <cstdint>
#include <cstddef>

// Problem constants
#define BB   64
#define NN   197
#define CC   768
#define HH   12
#define THD  16          // TOTAL_HEADS
#define DD   64
#define MROWS (BB*NN)    // 12608
#define QKVN (THD*DD)    // 1024
#define SCALE_ 0.125f
#define ATTS 208         // att row stride (f32)
#define KPAD 224         // P row k-padding (7*32)
#define SSTR 240         // S row stride (f32): 240%32=16 -> 2-way max (free)

typedef unsigned short u16;
typedef __attribute__((ext_vector_type(2))) float f32x2;
typedef __attribute__((ext_vector_type(4))) float f32x4;
typedef __attribute__((ext_vector_type(8))) short s16x8;
typedef __attribute__((address_space(1))) unsigned int as1_u32;
typedef __attribute__((address_space(3))) unsigned int as3_u32;

__device__ __forceinline__ float bf2f(u16 u) {
  union { unsigned int i; float f; } x; x.i = ((unsigned int)u) << 16; return x.f;
}
__device__ __forceinline__ u16 f2bf(float f) {
  unsigned int x = __builtin_bit_cast(unsigned int, f);
  unsigned int r = (x + 0x7fffu + ((x >> 16) & 1u)) >> 16;   // RNE
  return (u16)r;
}
__device__ __forceinline__ void gl_lds16(const u16* g, u16* l) {
  __builtin_amdgcn_global_load_lds((const as1_u32*)g, (as3_u32*)l, 16, 0, 0);
}

// ---------------- x (f32) -> bf16, 8 elems/thread ---------------------------
__global__ __launch_bounds__(256) void k_cvt_x(const float* __restrict__ src,
                                               u16* __restrict__ dst, int n8) {
  int i = blockIdx.x * 256 + threadIdx.x;
  if (i >= n8) return;
  const float4* s = (const float4*)src;
  float4 a = s[2 * i], b = s[2 * i + 1];
  ushort4 lo, hi;
  lo.x = f2bf(a.x); lo.y = f2bf(a.y); lo.z = f2bf(a.z); lo.w = f2bf(a.w);
  hi.x = f2bf(b.x); hi.y = f2bf(b.y); hi.z = f2bf(b.z); hi.w = f2bf(b.w);
  ((ushort4*)dst)[2 * i] = lo;
  ((ushort4*)dst)[2 * i + 1] = hi;
}

// ---------------- weight transpose+convert f32 (R,Ccol) -> bf16 (Ccol,R) ----
__global__ __launch_bounds__(256) void k_transpose(const float* __restrict__ in,
                                                   u16* __restrict__ out,
                                                   int R, int Ccol) {
  __shared__ u16 tile[32][33];
  int c0 = blockIdx.x * 32, r0 = blockIdx.y * 32;
  int tx = threadIdx.x & 31, ty = threadIdx.x >> 5;
#pragma unroll
  for (int i = 0; i < 32; i += 8) {
    int r = r0 + ty + i, c = c0 + tx;
    tile[ty + i][tx] = (r < R && c < Ccol) ? f2bf(in[(size_t)r * Ccol + c]) : (u16)0;
  }
  __syncthreads();
#pragma unroll
  for (int i = 0; i < 32; i += 8) {
    int cc = c0 + ty + i, rr = r0 + tx;
    if (cc < Ccol && rr < R) out[(size_t)cc * R + rr] = tile[tx][ty + i];
  }
}

// ---------------- bf16 MFMA GEMM: R18 = R14 counted-vmcnt pipeline at 128^2 -
// R13-R17 ran 256^2 tiles -> grid 200/150 blocks on a 256-CU chip: 22-41% of
// CUs IDLE and 1 block/CU (no cross-block latency cover). That, not pipeline
// depth, pinned the gemms at ~44-52us / MfmaUtil 12%. 128^2 x BK=32 x 3 bufs
// = 48 KB LDS -> 3 blocks/CU, grid 792/594 (3.1/2.3 per CU). Sync skeleton
// unchanged from R14 (verified): stage(t+2); vmcnt(8); barrier; compute;
// barrier. 4 loads/thread/tile -> vmcnt(8) = 2 tiles in flight; peel 4->0.
// Epilogue: R17 LDS-staged full-row bf16 writes (O[128][136], one pass).
__global__ __launch_bounds__(256, 3) void k_gemm_bt(const u16* __restrict__ A,
                                                    const u16* __restrict__ Bt,
                                                    const float* __restrict__ bias,
                                                    void* __restrict__ Cout,
                                                    int M, int Nn, int K,
                                                    int write_bf16) {
  __shared__ u16 SHG[24576];   // As=[0,12288) 3x4096 | Bs=[12288,24576) 3x4096
                               // epilogue reuse: O[128][136] = 17408 u16
  u16* As = SHG;
  u16* Bs = SHG + 12288;
  int t = threadIdx.x;
  int w = t >> 6, lane = t & 63;

  // XCD-chunked bijective remap (m204)
  int NT = gridDim.y;
  int nwg = gridDim.x * gridDim.y;
  int d = blockIdx.y * gridDim.x + blockIdx.x;
  int q8 = nwg >> 3, r8 = nwg & 7;
  int xcd = d & 7, j = d >> 3;
  int g = (xcd < r8 ? xcd * (q8 + 1) : r8 * (q8 + 1) + (xcd - r8) * q8) + j;
  int mt = g / NT, nt_ = g - mt * NT;
  int m0 = mt * 128, n0 = nt_ * 128;

  int wm = w >> 1, wn = w & 1;                      // 2 x 2 wave grid

  f32x4 acc[4][4];
#pragma unroll
  for (int i = 0; i < 4; i++)
#pragma unroll
    for (int j2 = 0; j2 < 4; j2++)
#pragma unroll
      for (int e = 0; e < 4; e++) acc[i][j2][e] = 0.f;

  int lrow4 = lane >> 2;       // 0..15
  int lkc = (lane & 3) * 8;    // 0,8,16,24

  // stage one BK=32 K-tile (A 8KB + B 8KB): chunk = 16 rows x 32 k = 1 KB;
  // c = w + rc*4 (0..7). 4 VMEM per thread per tile (2 A + 2 B).
  auto stage = [&](int buf, int kk) {
#pragma unroll
    for (int rc = 0; rc < 2; rc++) {
      int c = w + rc * 4;
      int row = c * 16 + lrow4;
      int ga = m0 + row; if (ga >= M) ga = M - 1;
      gl_lds16(A + (size_t)ga * K + kk + lkc, &As[buf * 4096 + c * 512]);
      gl_lds16(Bt + (size_t)(n0 + row) * K + kk + lkc, &Bs[buf * 4096 + c * 512]);
    }
  };

  auto compute = [&](int buf) {
    int r16 = lane & 15, k8 = (lane >> 4) * 8;
    s16x8 af[4], bfv[4];
#pragma unroll
    for (int s = 0; s < 4; s++) {
      af[s]  = *(const s16x8*)&As[buf * 4096 + (wm * 64 + s * 16 + r16) * 32 + k8];
      bfv[s] = *(const s16x8*)&Bs[buf * 4096 + (wn * 64 + s * 16 + r16) * 32 + k8];
    }
#pragma unroll
    for (int sm = 0; sm < 4; sm++)
#pragma unroll
      for (int sn = 0; sn < 4; sn++)
        acc[sm][sn] = __builtin_amdgcn_mfma_f32_16x16x32_bf16(af[sm], bfv[sn], acc[sm][sn], 0, 0, 0);
  };

  int nt = K >> 5;                  // 24 for K=768
  stage(0, 0);
  stage(1, 32);
  for (int tt = 0; tt < nt - 2; ++tt) {
    stage((tt + 2) % 3, (tt + 2) * 32);
    asm volatile("s_waitcnt vmcnt(8)" ::: "memory");
    __builtin_amdgcn_sched_barrier(0);
    __builtin_amdgcn_s_barrier();
    compute(tt % 3);
    __builtin_amdgcn_s_barrier();
  }
  asm volatile("s_waitcnt vmcnt(4)" ::: "memory");
  __builtin_amdgcn_sched_barrier(0);
  __builtin_amdgcn_s_barrier();
  compute((nt - 2) % 3);
  __builtin_amdgcn_s_barrier();
  asm volatile("s_waitcnt vmcnt(0)" ::: "memory");
  __builtin_amdgcn_sched_barrier(0);
  __builtin_amdgcn_s_barrier();
  compute((nt - 1) % 3);

  int quad = lane >> 4, col = lane & 15;
  if (write_bf16) {
    u16* Cb = (u16*)Cout;
    u16* O = SHG;                        // [128][136] u16
    __syncthreads();                     // all LDS reads done before O overwrite
#pragma unroll
    for (int sn = 0; sn < 4; sn++) {
      int gn = n0 + wn * 64 + sn * 16 + col;
      float bv = bias[gn];
#pragma unroll
      for (int sm = 0; sm < 4; sm++)
#pragma unroll
        for (int i = 0; i < 4; i++)
          O[(wm * 64 + sm * 16 + quad * 4 + i) * 136 + wn * 64 + sn * 16 + col] =
              f2bf(acc[sm][sn][i] + bv);
    }
    __syncthreads();
    // copy out: 128 rows x 16 chunks of 16 B; 16 lanes cover a full 256-B row
#pragma unroll
    for (int it = 0; it < 8; it++) {
      int q = t + it * 256;
      int rl = q >> 4, c8 = q & 15;
      int gm = m0 + rl;
      if (gm < M) {
        s16x8 v = *(const s16x8*)&O[rl * 136 + c8 * 8];
        *(s16x8*)&Cb[(size_t)gm * Nn + n0 + c8 * 8] = v;
      }
    }
  } else {
    float* Cf = (float*)Cout;
#pragma unroll
    for (int sn = 0; sn < 4; sn++) {
      int gn = n0 + wn * 64 + sn * 16 + col;
      float bv = bias[gn];
#pragma unroll
      for (int sm = 0; sm < 4; sm++) {
        int gmb = m0 + wm * 64 + sm * 16 + quad * 4;
#pragma unroll
        for (int i = 0; i < 4; i++) {
          int gm = gmb + i;
          if (gm < M) Cf[(size_t)gm * Nn + gn] = acc[sm][sn][i] + bv;
        }
      }
    }
  }
}

// ---------------- QK^T logits via MFMA (R14 verbatim) -----------------------
__global__ __launch_bounds__(256) void k_qk(const u16* __restrict__ qkv,
                                            float* __restrict__ att) {
  __shared__ u16 As[2][128 * 32];
  __shared__ u16 Bs[2][128 * 32];
  int t = threadIdx.x;
  int w = t >> 6, lane = t & 63;
  int bz = blockIdx.z, b = bz >> 1, g = bz & 1;
  int n0 = blockIdx.x * 128;     // Q rows
  int m0 = blockIdx.y * 128;     // K rows
  int wm = w >> 1, wn = w & 1;

  f32x4 acc[4][4];
#pragma unroll
  for (int i = 0; i < 4; i++)
#pragma unroll
    for (int j = 0; j < 4; j++)
#pragma unroll
      for (int e = 0; e < 4; e++) acc[i][j][e] = 0.f;

  int lrow4 = lane >> 2, lkc = (lane & 3) * 8;

#pragma unroll
  for (int half = 0; half < 2; half++) {
    int kk = half * 32;
#pragma unroll
    for (int rc = 0; rc < 2; rc++) {
      int c = w + rc * 4;
      int row = c * 16 + lrow4;
      int nq = n0 + row; if (nq > NN - 1) nq = NN - 1;
      int mk = m0 + row; if (mk > NN - 1) mk = NN - 1;
      gl_lds16(qkv + (size_t)(b * NN + nq) * QKVN + g * DD + kk + lkc, &As[half][c * 512]);
      gl_lds16(qkv + (size_t)(b * NN + mk) * QKVN + 2 * DD + g * DD + kk + lkc, &Bs[half][c * 512]);
    }
  }
  __syncthreads();
  {
    int r16 = lane & 15, k8 = (lane >> 4) * 8;
#pragma unroll
    for (int half = 0; half < 2; half++) {
      s16x8 af[4], bfv[4];
#pragma unroll
      for (int s = 0; s < 4; s++) {
        af[s]  = *(const s16x8*)&As[half][(wm * 64 + s * 16 + r16) * 32 + k8];
        bfv[s] = *(const s16x8*)&Bs[half][(wn * 64 + s * 16 + r16) * 32 + k8];
      }
#pragma unroll
      for (int sm = 0; sm < 4; sm++)
#pragma unroll
        for (int sn = 0; sn < 4; sn++)
          acc[sm][sn] = __builtin_amdgcn_mfma_f32_16x16x32_bf16(af[sm], bfv[sn], acc[sm][sn], 0, 0, 0);
    }
  }
  int quad = lane >> 4, col = lane & 15;
#pragma unroll
  for (int sn = 0; sn < 4; sn++) {
    int gn = m0 + wn * 64 + sn * 16 + col;          // key index m
#pragma unroll
    for (int sm = 0; sm < 4; sm++) {
      int gmb = n0 + wm * 64 + sm * 16 + quad * 4;  // query index n
#pragma unroll
      for (int i = 0; i < 4; i++) {
        int gm = gmb + i;
        if (gm < NN && gn < NN)
          att[((size_t)bz * NN + gm) * ATTS + gn] = acc[sm][sn][i] * SCALE_;
      }
    }
  }
}

// ---------------- per (b,n): mask-mix + relu + head-proj + softmax -> P -----
// R11/R14 verbatim: SSTR=240, register-cached max pass, deferred 1/sum.
__global__ __launch_bounds__(256) void k_softmax_p(const float* __restrict__ att,
                                                   const float* __restrict__ masks,
                                                   const float* __restrict__ mproj,
                                                   const float* __restrict__ mbase,
                                                   const float* __restrict__ hpw,
                                                   const float* __restrict__ hpb,
                                                   u16* __restrict__ P) {
  __shared__ float S[12][SSTR];
  __shared__ f32x2 hpw_s[72];
  __shared__ f32x2 mp_s[18];
  __shared__ f32x2 mb_s[6], hpb_s[6];
  __shared__ float inv_s[12];
  int t = threadIdx.x;
  int n = blockIdx.x, b = blockIdx.y;

  if (t < 72) hpw_s[t] = ((const f32x2*)hpw)[t];
  if (t < 18) mp_s[t] = ((const f32x2*)mproj)[t];
  if (t < 6) { mb_s[t] = ((const f32x2*)mbase)[t]; hpb_s[t] = ((const f32x2*)hpb)[t]; }
  __syncthreads();

  if (t < NN) {
    int m = t;
    float a0 = att[((size_t)(b * 2 + 0) * NN + n) * ATTS + m];
    float a1 = att[((size_t)(b * 2 + 1) * NN + n) * ATTS + m];
    const float* mk = masks + ((size_t)n * NN + m) * 3;
    float l0 = mk[0], l1 = mk[1], l2 = mk[2];
    f32x2 pre2[6];
#pragma unroll
    for (int k = 0; k < 6; k++) {
      f32x2 wv = mb_s[k] + l0 * mp_s[k] + l1 * mp_s[6 + k] + l2 * mp_s[12 + k];
      float av = (k < 3) ? a0 : a1;
      f32x2 v = wv * av;
      pre2[k].x = v.x > 0.f ? v.x : 0.f;
      pre2[k].y = v.y > 0.f ? v.y : 0.f;
    }
    f32x2 s2[6];
#pragma unroll
    for (int k = 0; k < 6; k++) s2[k] = hpb_s[k];
#pragma unroll
    for (int h = 0; h < 12; h++) {
      float p = (h & 1) ? pre2[h >> 1].y : pre2[h >> 1].x;
#pragma unroll
      for (int k = 0; k < 6; k++) s2[k] += p * hpw_s[h * 6 + k];
    }
#pragma unroll
    for (int k = 0; k < 6; k++) {
      S[2 * k][m] = s2[k].x;
      S[2 * k + 1][m] = s2[k].y;
    }
  } else if (t < KPAD) {
#pragma unroll
    for (int h = 0; h < 12; h++) S[h][t] = 0.f;
  }
  __syncthreads();

  {
    int g = t >> 4, l16 = t & 15;
    if (g < 12) {
      float vals[13];
      float mx = -1e30f;
#pragma unroll
      for (int i = 0; i < 13; i++) {
        int m = l16 + i * 16;
        float x = S[g][m];
        vals[i] = (m < NN) ? x : -1e30f;
        mx = fmaxf(mx, vals[i]);
      }
#pragma unroll
      for (int off = 8; off; off >>= 1) mx = fmaxf(mx, __shfl_xor(mx, off, 16));
      float sum = 0.f;
#pragma unroll
      for (int i = 0; i < 13; i++) {
        int m = l16 + i * 16;
        float e = __expf(vals[i] - mx);
        if (m < NN) { S[g][m] = e; sum += e; }
      }
#pragma unroll
      for (int off = 8; off; off >>= 1) sum += __shfl_xor(sum, off, 16);
      if (l16 == 0) inv_s[g] = 1.f / sum;
    }
  }
  __syncthreads();

  for (int c4 = t; c4 < 672; c4 += 256) {
    int h = c4 / 56;
    int m = (c4 - h * 56) * 4;
    f32x4 v = *(const f32x4*)&S[h][m];
    float iv = inv_s[h];
    ushort4 u;
    u.x = f2bf(v.x * iv); u.y = f2bf(v.y * iv);
    u.z = f2bf(v.z * iv); u.w = f2bf(v.w * iv);
    *(ushort4*)(P + ((size_t)(b * HH + h) * NN + n) * KPAD + m) = u;
  }
}

// ---------------- PV via MFMA (R17: single 224-row block; LDS-staged aout) --
__global__ __launch_bounds__(256) void k_pv(const u16* __restrict__ P,
                                            const u16* __restrict__ qkv,
                                            u16* __restrict__ aout) {
  __shared__ u16 SH[18432];   // As=[0,14336) 2x7168 | Bs=[14336,18432) 2x2048
                              // epilogue reuse: O[224][80] = 17920 u16
  u16* As = SH;
  u16* Bs = SH + 14336;
  int t = threadIdx.x;
  int w = t >> 6, lane = t & 63;
  int bh = blockIdx.x, b = bh / HH, h = bh - b * HH;

  f32x4 acc[4][4];
#pragma unroll
  for (int i = 0; i < 4; i++)
#pragma unroll
    for (int j = 0; j < 4; j++)
#pragma unroll
      for (int e = 0; e < 4; e++) acc[i][j][e] = 0.f;

  int lrow4 = lane >> 2, lkc = (lane & 3) * 8;
  int vml = t & 31, vd0 = (t >> 5) * 8;

  for (int k0 = 0; k0 < KPAD; k0 += 64) {
    int nh = (KPAD - k0 >= 64) ? 2 : 1;
    for (int half = 0; half < nh; half++) {
      int kk = k0 + half * 32;
#pragma unroll
      for (int rc = 0; rc < 4; rc++) {
        int c = w + rc * 4;
        if (c < 14) {
          int row = c * 16 + lrow4;
          int gn = row > NN - 1 ? NN - 1 : row;
          gl_lds16(P + ((size_t)bh * NN + gn) * KPAD + kk + lkc, &As[half * 7168 + c * 512]);
        }
      }
      {
        int m = kk + vml;
        u16 v8[8];
        if (m < NN) {
          const ushort4* vp = (const ushort4*)(qkv + (size_t)(b * NN + m) * QKVN + (4 + h) * DD + vd0);
          ushort4 lo = vp[0], hi = vp[1];
          v8[0] = lo.x; v8[1] = lo.y; v8[2] = lo.z; v8[3] = lo.w;
          v8[4] = hi.x; v8[5] = hi.y; v8[6] = hi.z; v8[7] = hi.w;
        } else {
#pragma unroll
          for (int j = 0; j < 8; j++) v8[j] = 0;
        }
#pragma unroll
        for (int j = 0; j < 8; j++) Bs[half * 2048 + (vd0 + j) * 32 + vml] = v8[j];
      }
    }
    __syncthreads();
    int r16 = lane & 15, k8 = (lane >> 4) * 8;
    for (int half = 0; half < nh; half++) {
      s16x8 bfv[4];
#pragma unroll
      for (int s = 0; s < 4; s++)
        bfv[s] = *(const s16x8*)&Bs[half * 2048 + (s * 16 + r16) * 32 + k8];
#pragma unroll
      for (int si = 0; si < 4; si++) {
        int smt = w + si * 4;
        if (smt < 14) {
          s16x8 af = *(const s16x8*)&As[half * 7168 + (smt * 16 + r16) * 32 + k8];
#pragma unroll
          for (int sn = 0; sn < 4; sn++)
            acc[si][sn] = __builtin_amdgcn_mfma_f32_16x16x32_bf16(af, bfv[sn], acc[si][sn], 0, 0, 0);
        }
      }
    }
    __syncthreads();
  }

  int quad = lane >> 4, col = lane & 15;
  u16* O = SH;
#pragma unroll
  for (int si = 0; si < 4; si++) {
    int smt = w + si * 4;
    if (smt < 14) {
#pragma unroll
      for (int sn = 0; sn < 4; sn++)
#pragma unroll
        for (int i = 0; i < 4; i++)
          O[(smt * 16 + quad * 4 + i) * 80 + sn * 16 + col] = f2bf(acc[si][sn][i]);
    }
  }
  __syncthreads();
  for (int q = t; q < NN * 8; q += 256) {
    int rl = q >> 3, c8 = q & 7;
    s16x8 v = *(const s16x8*)&O[rl * 80 + c8 * 8];
    *(s16x8*)&aout[(size_t)(b * NN + rl) * CC + h * DD + c8 * 8] = v;
  }
}

extern "C" void kernel_launch(void* const* d_in, const int* in_sizes, int n_in,
                              void* d_out, int out_size, void* d_ws, size_t ws_size,
                              hipStream_t stream) {
  const float* x     = (const float*)d_in[0];
  const float* qkv_w = (const float*)d_in[1];
  const float* qkv_b = (const float*)d_in[2];
  const float* masks = (const float*)d_in[3];
  const float* mproj = (const float*)d_in[4];
  const float* mbase = (const float*)d_in[5];
  const float* hpw   = (const float*)d_in[6];
  const float* hpb   = (const float*)d_in[7];
  const float* projw = (const float*)d_in[8];
  const float* projb = (const float*)d_in[9];

  char* ws = (char*)d_ws;
  size_t off = 0;
  auto alloc = [&](size_t bytes) {
    char* p = ws + off; off = (off + bytes + 255) & ~(size_t)255; return p;
  };
  // region1: xbf (19.4MB) -> att (21.0MB) -> aout (19.4MB), disjoint lifetimes
  char*  r1   = alloc((size_t)BB * 2 * NN * ATTS * 4);
  u16*   xbf  = (u16*)r1;
  float* att  = (float*)r1;
  u16*   aout = (u16*)r1;
  u16*   qkv  = (u16*)alloc((size_t)MROWS * QKVN * 2);          // 25.8 MB
  u16*   P    = (u16*)alloc((size_t)BB * HH * NN * KPAD * 2);   // 67.8 MB
  u16*   wt1  = (u16*)alloc((size_t)QKVN * CC * 2);             //  1.6 MB
  u16*   wt2  = (u16*)alloc((size_t)CC * CC * 2);               //  1.2 MB

  int n8 = MROWS * CC / 8;
  k_cvt_x<<<(n8 + 255) / 256, 256, 0, stream>>>(x, xbf, n8);
  k_transpose<<<dim3(QKVN / 32, CC / 32), 256, 0, stream>>>(qkv_w, wt1, CC, QKVN);
  k_transpose<<<dim3(CC / 32, CC / 32), 256, 0, stream>>>(projw, wt2, CC, CC);
  // qkv = x @ qkv_w + qkv_b (bf16; 128^2 tiles, 3 blocks/CU, LDS epilogue)
  k_gemm_bt<<<dim3((MROWS + 127) / 128, QKVN / 128), 256, 0, stream>>>(
      xbf, wt1, qkv_b, qkv, MROWS, QKVN, CC, 1);
  // att[bg][n][m] = SCALE * q.k
  k_qk<<<dim3(2, 2, BB * 2), 256, 0, stream>>>(qkv, att);
  // P[b][h][n][m] (bf16, softmaxed)
  k_softmax_p<<<dim3(NN, BB), 256, 0, stream>>>(att, masks, mproj, mbase, hpw, hpb, P);
  // aout[b][n][h*64+d] = P @ V  (single 224-row block per bh)
  k_pv<<<dim3(BB * HH), 256, 0, stream>>>(P, qkv, aout);
  // out = aout @ proj_w + proj_b (f32; 128^2 tiles)
  k_gemm_bt<<<dim3((MROWS + 127) / 128, CC / 128), 256, 0, stream>>>(
      aout, wt2, projb, d_out, MROWS, CC, CC, 0);
}